// Round 6
// baseline (94.600 us; speedup 1.0000x reference)
//
#include <hip/hip_runtime.h>
#include <hip/hip_bf16.h>

// FMICLLoss: out = -mean(s_pos) + ALPHA * ( sum_{i!=j} exp(-d2_ij/2) / (N(N-1)) + EPS )
// N=8192, D=256, SIGMA=1 (inv2s2=0.5), ALPHA=1.5, EPS=1e-8, NORM_EPS=1e-12.
//
// Round 6: persistent, software-pipelined pair kernel.
// Diagnosis: R5's stage->barrier structure exposes the full ~1200cyc staging
// drain on every tile (prefetch issued immediately before the barrier that
// drains it == m97 plateau). Fix: 256 persistent blocks (1/CU), double-
// buffered full-K tiles (2 x 64 KB LDS), prefetch tile t+1 issued right AFTER
// the barrier that publishes tile t, so it has the whole compute phase
// (~1900 cyc) to land before its own drain. Per-tile cross-wave reductions
// removed (per-lane register accumulation across tiles; one store per block).
// MX-fp8 mfma_scale 16x16x128, XOR-swizzled LDS, zero atomics.
// ~47us of dur_us is harness ws re-poison fill + input restore (untouchable).

#define N_ROWS 8192
#define DIM    256
#define LOG2E  1.4426950408889634f
#define NBLK   2080
#define GRID   256

typedef __attribute__((ext_vector_type(8))) int   int8v;
typedef __attribute__((ext_vector_type(4))) float f32x4;

#define GLDS16(gptr, lptr) \
  __builtin_amdgcn_global_load_lds((const __attribute__((address_space(1))) void*)(gptr), \
                                   (__attribute__((address_space(3))) void*)(lptr), 16, 0, 0)

// ---------------------------------------------------------------------------
// Kernel 1: row-normalize z1,z2; write z1n8 (fp8 e4m3) + hl[i]=0.5*log2e*||z||^2;
// per-block s_pos partial. One wave per row. No atomics.
// ---------------------------------------------------------------------------
__global__ __launch_bounds__(256) void norm_kernel(
    const float* __restrict__ z1, const float* __restrict__ z2,
    unsigned char* __restrict__ z1n8, float* __restrict__ hl,
    float* __restrict__ spos_part) {

    int tid  = threadIdx.x;
    int wave = tid >> 6, lane = tid & 63;
    int row  = blockIdx.x * 4 + wave;

    const float4 a = *(const float4*)(z1 + (size_t)row * DIM + lane * 4);
    const float4 b = *(const float4*)(z2 + (size_t)row * DIM + lane * 4);

    float s1 = a.x*a.x + a.y*a.y + a.z*a.z + a.w*a.w;
    float s2 = b.x*b.x + b.y*b.y + b.z*b.z + b.w*b.w;
    #pragma unroll
    for (int off = 32; off; off >>= 1) {
        s1 += __shfl_xor(s1, off);
        s2 += __shfl_xor(s2, off);
    }
    float m1 = fmaxf(sqrtf(s1), 1e-12f);
    float m2 = fmaxf(sqrtf(s2), 1e-12f);

    float4 an = make_float4(a.x/m1, a.y/m1, a.z/m1, a.w/m1);
    float4 bn = make_float4(b.x/m2, b.y/m2, b.z/m2, b.w/m2);

    float dx = an.x - bn.x, dy = an.y - bn.y, dz = an.z - bn.z, dw = an.w - bn.w;
    float dp = dx*dx + dy*dy + dz*dz + dw*dw;
    #pragma unroll
    for (int off = 32; off; off >>= 1) dp += __shfl_xor(dp, off);

    // pack 4 fp8 e4m3 (OCP) and store 4B/lane (coalesced 256B/row)
    int lo = __builtin_amdgcn_cvt_pk_fp8_f32(an.x, an.y, 0,  false);
    int pk = __builtin_amdgcn_cvt_pk_fp8_f32(an.z, an.w, lo, true);
    ((int*)(z1n8 + (size_t)row * DIM))[lane] = pk;

    __shared__ float sp[4];
    if (lane == 0) {
        float sqn = s1 / (m1 * m1);                      // ||z1n||^2 (fp32-exact)
        hl[row] = 0.5f * LOG2E * sqn;
        sp[wave] = logf(expf(-dp * 0.5f) + 1e-8f) + 1.0f;  // s_pos
    }
    __syncthreads();
    if (tid == 0)
        spos_part[blockIdx.x] = sp[0] + sp[1] + sp[2] + sp[3];
}

// ---------------------------------------------------------------------------
// Kernel 2: persistent fused fp8 Z·Z^T + exp-sum. 256 blocks, ~8 tiles each.
// Double-buffered full-K 128x256 fp8 tiles; prefetch(t+1) issued right after
// the barrier publishing tile t -> drain hidden under compute. One barrier
// per tile. Per-lane accumulation across tiles; one partial store per block.
// ---------------------------------------------------------------------------
__global__ __launch_bounds__(256) void pair_kernel(
    const unsigned char* __restrict__ z1n8, const float* __restrict__ hl,
    float* __restrict__ negp_part) {

    __shared__ unsigned char S[2][2][128 * 256];   // [buf][A=0/B=1] : 128 KB
    __shared__ float red[4];

    int tid  = threadIdx.x;
    int wave = tid >> 6, lane = tid & 63;
    int wr = wave >> 1, wc = wave & 1;
    int quad = lane >> 4, colL = lane & 15;
    const int c7 = colL & 7;

    // staging lane mapping: per issue, 64 lanes x 16B = 4 rows of 256B
    int rl = lane >> 4, cl = lane & 15;
    const size_t offE = (size_t)(wave * 32 +     rl) * DIM + ((cl ^  rl     ) << 4);
    const size_t offO = (size_t)(wave * 32 + 4 + rl) * DIM + ((cl ^ (rl + 4)) << 4);
    const int dstW = (wave * 32) * 256;

    // triangular decode: tile t -> (bi, bj), bi <= bj
    auto decode = [](int t, int& bi, int& bj) {
        int u = NBLK - 1 - t;
        int k = (int)((sqrtf(8.0f * (float)u + 1.0f) - 1.0f) * 0.5f);
        while ((k + 1) * (k + 2) / 2 <= u) ++k;
        while (k * (k + 1) / 2 > u) --k;
        bi = 63 - k;
        bj = 63 - (u - k * (k + 1) / 2);
    };

    auto stage = [&](int buf, int bi, int bj) {
        const unsigned char* gA = z1n8 + (size_t)bi * (128 * DIM);
        const unsigned char* gB = z1n8 + (size_t)bj * (128 * DIM);
        unsigned char* dA = &S[buf][0][dstW];
        unsigned char* dB = &S[buf][1][dstW];
        #pragma unroll
        for (int h = 0; h < 4; ++h) {          // 8 rows (2KB) per h
            GLDS16(gA + offE + h * 2048, dA + (2*h    ) * 1024);
            GLDS16(gA + offO + h * 2048, dA + (2*h + 1) * 1024);
            GLDS16(gB + offE + h * 2048, dB + (2*h    ) * 1024);
            GLDS16(gB + offO + h * 2048, dB + (2*h + 1) * 1024);
        }
    };

    float total = 0.0f;
    int t = blockIdx.x;
    int bi, bj, nbi = 0, nbj = 0;
    decode(t, bi, bj);
    stage(0, bi, bj);

    for (int it = 0; t < NBLK; t += GRID, ++it) {
        int cur = it & 1;
        int nt = t + GRID;
        bool havenext = (nt < NBLK);
        if (havenext) decode(nt, nbi, nbj);

        __syncthreads();                 // publishes buf[cur]; buf[1-cur] free
        if (havenext) stage(1 - cur, nbi, nbj);

        // ---- compute tile (bi, bj) from S[cur] ----
        const unsigned char* A = S[cur][0];
        const unsigned char* B = S[cur][1];
        f32x4 accf[4][4] = {};

        #pragma unroll
        for (int ks = 0; ks < 2; ++ks) {     // two K=128 steps, no barriers
            int8v af[4], bf[4];
            #pragma unroll
            for (int m = 0; m < 4; ++m) {
                int base = (wr * 64 + m * 16 + colL) * 256;
                int sb0 = ks * 8 + ((quad * 2    ) ^ c7);
                int sb1 = ks * 8 + ((quad * 2 + 1) ^ c7);
                union { int8v v; uint4 q[2]; } u8;
                u8.q[0] = *(const uint4*)&A[base + (sb0 << 4)];
                u8.q[1] = *(const uint4*)&A[base + (sb1 << 4)];
                af[m] = u8.v;
            }
            #pragma unroll
            for (int n = 0; n < 4; ++n) {
                int base = (wc * 64 + n * 16 + colL) * 256;
                int sb0 = ks * 8 + ((quad * 2    ) ^ c7);
                int sb1 = ks * 8 + ((quad * 2 + 1) ^ c7);
                union { int8v v; uint4 q[2]; } u8;
                u8.q[0] = *(const uint4*)&B[base + (sb0 << 4)];
                u8.q[1] = *(const uint4*)&B[base + (sb1 << 4)];
                bf[n] = u8.v;
            }
            #pragma unroll
            for (int m = 0; m < 4; ++m)
                #pragma unroll
                for (int n = 0; n < 4; ++n)
                    accf[m][n] = __builtin_amdgcn_mfma_scale_f32_16x16x128_f8f6f4(
                        af[m], bf[n], accf[m][n],
                        0 /*fmtA=fp8*/, 0 /*fmtB=fp8*/,
                        0, 0x7F7F7F7F,   // scale A = 1.0 (E8M0 127)
                        0, 0x7F7F7F7F);  // scale B = 1.0
        }

        // epilogue: term = exp2(min(dot*log2e - h_i - h_j, 0)), skip i==j
        float local = 0.0f;
        float hjn[4];
        #pragma unroll
        for (int n = 0; n < 4; ++n)
            hjn[n] = hl[bj * 128 + wc * 64 + n * 16 + colL];

        if (bi != bj) {
            #pragma unroll
            for (int m = 0; m < 4; ++m) {
                #pragma unroll
                for (int reg = 0; reg < 4; ++reg) {
                    float hi = hl[bi * 128 + wr * 64 + m * 16 + quad * 4 + reg];
                    #pragma unroll
                    for (int n = 0; n < 4; ++n) {
                        float arg = fminf(accf[m][n][reg] * LOG2E - hi - hjn[n], 0.0f);
                        local += __builtin_amdgcn_exp2f(arg);
                    }
                }
            }
            local *= 2.0f;                   // mirrored block
        } else {
            #pragma unroll
            for (int m = 0; m < 4; ++m) {
                #pragma unroll
                for (int reg = 0; reg < 4; ++reg) {
                    int i = wr * 64 + m * 16 + quad * 4 + reg;
                    float hi = hl[bi * 128 + i];
                    #pragma unroll
                    for (int n = 0; n < 4; ++n) {
                        int j = wc * 64 + n * 16 + colL;
                        float arg = fminf(accf[m][n][reg] * LOG2E - hi - hjn[n], 0.0f);
                        float e = __builtin_amdgcn_exp2f(arg);
                        local += (i == j) ? 0.0f : e;
                    }
                }
            }
        }
        total += local;
        bi = nbi; bj = nbj;
    }

    // block-level reduction, once per kernel
    #pragma unroll
    for (int off = 32; off; off >>= 1) total += __shfl_down(total, off);
    if (lane == 0) red[wave] = total;
    __syncthreads();
    if (tid == 0)
        negp_part[blockIdx.x] = red[0] + red[1] + red[2] + red[3];
}

// ---------------------------------------------------------------------------
// Kernel 3: finalize — reduce partials in double, emit scalar.
// ---------------------------------------------------------------------------
__global__ __launch_bounds__(256) void finalize_kernel(
    const float* __restrict__ spos_part, const float* __restrict__ negp_part,
    float* __restrict__ out) {

    int tid = threadIdx.x;
    double s = 0.0, ng = 0.0;
    for (int i = tid; i < 2048; i += 256) s  += (double)spos_part[i];
    if (tid < GRID) ng = (double)negp_part[tid];

    #pragma unroll
    for (int off = 32; off; off >>= 1) {
        s  += __shfl_xor(s,  off);
        ng += __shfl_xor(ng, off);
    }
    __shared__ double sd[4], nd[4];
    int wave = tid >> 6, lane = tid & 63;
    if (lane == 0) { sd[wave] = s; nd[wave] = ng; }
    __syncthreads();
    if (tid == 0) {
        double st = sd[0] + sd[1] + sd[2] + sd[3];
        double nt = nd[0] + nd[1] + nd[2] + nd[3];
        double mean_star = nt / (8192.0 * 8191.0) + 1e-8;
        out[0] = (float)(-st / 8192.0 + 1.5 * mean_star);
    }
}

extern "C" void kernel_launch(void* const* d_in, const int* in_sizes, int n_in,
                              void* d_out, int out_size, void* d_ws, size_t ws_size,
                              hipStream_t stream) {
    const float* z1 = (const float*)d_in[0];
    const float* z2 = (const float*)d_in[1];
    float* out = (float*)d_out;

    char* ws = (char*)d_ws;
    float* hl            = (float*)ws;                                 // 32 KB
    unsigned char* z1n8  = (unsigned char*)(ws + N_ROWS * 4);          // 2 MB fp8
    float* spos_part     = (float*)(ws + N_ROWS * 4 + N_ROWS * DIM);   // 8 KB
    float* negp_part     = spos_part + 2048;                           // 1 KB

    norm_kernel<<<N_ROWS / 4, 256, 0, stream>>>(z1, z2, z1n8, hl, spos_part);
    pair_kernel<<<GRID, 256, 0, stream>>>(z1n8, hl, negp_part);
    finalize_kernel<<<1, 256, 0, stream>>>(spos_part, negp_part, out);
}

// Round 8
// 88.214 us; speedup vs baseline: 1.0724x; 1.0724x over previous
//
#include <hip/hip_runtime.h>
#include <hip/hip_bf16.h>

// FMICLLoss: out = -mean(s_pos) + ALPHA * ( sum_{i!=j} exp(-d2_ij/2) / (N(N-1)) + EPS )
// N=8192, D=256, SIGMA=1 (inv2s2=0.5), ALPHA=1.5, EPS=1e-8, NORM_EPS=1e-12.
//
// Round 8: cooperative launch (R7) never ran — runtime rejected the config
// silently (65.6KB static LDS vs the coop validator's 64KB budget). Dropped.
// Back to 3 dispatches; pair is now PERSISTENT grid=512 (2 blocks/CU, pinned
// via __launch_bounds__(256,2)) with K=128-chunk double buffering (2x32KB
// LDS): each chunk's global_load_lds DMA is issued one full compute phase
// (~1100cyc MFMA) before the barrier that drains it -> drain ~free, and TLP
// from 2 blocks/CU retained (R6 had the pipeline but only 1 block/CU; R5 had
// occupancy but exposed drains). MX-fp8 mfma_scale 16x16x128, XOR-swizzled
// LDS, zero atomics.
// ~48us of dur_us is harness ws re-poison fill + input restore (untouchable).

#define N_ROWS 8192
#define DIM    256
#define LOG2E  1.4426950408889634f
#define NBLK   2080
#define GRID   512

typedef __attribute__((ext_vector_type(8))) int   int8v;
typedef __attribute__((ext_vector_type(4))) float f32x4;

#define GLDS16(gptr, lptr) \
  __builtin_amdgcn_global_load_lds((const __attribute__((address_space(1))) void*)(gptr), \
                                   (__attribute__((address_space(3))) void*)(lptr), 16, 0, 0)

__device__ inline void tri_decode(int t, int& bi, int& bj) {
    int u = NBLK - 1 - t;
    int k = (int)((sqrtf(8.0f * (float)u + 1.0f) - 1.0f) * 0.5f);
    while ((k + 1) * (k + 2) / 2 <= u) ++k;
    while (k * (k + 1) / 2 > u) --k;
    bi = 63 - k;
    bj = 63 - (u - k * (k + 1) / 2);
}

// ---------------------------------------------------------------------------
// Kernel 1: row-normalize z1,z2; write z1n8 (fp8 e4m3) + hl[i]=0.5*log2e*||z||^2;
// per-block s_pos partial. One wave per row. No atomics.
// ---------------------------------------------------------------------------
__global__ __launch_bounds__(256) void norm_kernel(
    const float* __restrict__ z1, const float* __restrict__ z2,
    unsigned char* __restrict__ z1n8, float* __restrict__ hl,
    float* __restrict__ spos_part) {

    int tid  = threadIdx.x;
    int wave = tid >> 6, lane = tid & 63;
    int row  = blockIdx.x * 4 + wave;

    const float4 a = *(const float4*)(z1 + (size_t)row * DIM + lane * 4);
    const float4 b = *(const float4*)(z2 + (size_t)row * DIM + lane * 4);

    float s1 = a.x*a.x + a.y*a.y + a.z*a.z + a.w*a.w;
    float s2 = b.x*b.x + b.y*b.y + b.z*b.z + b.w*b.w;
    #pragma unroll
    for (int off = 32; off; off >>= 1) {
        s1 += __shfl_xor(s1, off);
        s2 += __shfl_xor(s2, off);
    }
    float m1 = fmaxf(sqrtf(s1), 1e-12f);
    float m2 = fmaxf(sqrtf(s2), 1e-12f);

    float4 an = make_float4(a.x/m1, a.y/m1, a.z/m1, a.w/m1);
    float4 bn = make_float4(b.x/m2, b.y/m2, b.z/m2, b.w/m2);

    float dx = an.x - bn.x, dy = an.y - bn.y, dz = an.z - bn.z, dw = an.w - bn.w;
    float dp = dx*dx + dy*dy + dz*dz + dw*dw;
    #pragma unroll
    for (int off = 32; off; off >>= 1) dp += __shfl_xor(dp, off);

    // pack 4 fp8 e4m3 (OCP) and store 4B/lane (coalesced 256B/row)
    int lo = __builtin_amdgcn_cvt_pk_fp8_f32(an.x, an.y, 0,  false);
    int pk = __builtin_amdgcn_cvt_pk_fp8_f32(an.z, an.w, lo, true);
    ((int*)(z1n8 + (size_t)row * DIM))[lane] = pk;

    __shared__ float sp[4];
    if (lane == 0) {
        float sqn = s1 / (m1 * m1);                      // ||z1n||^2 (fp32-exact)
        hl[row] = 0.5f * LOG2E * sqn;
        sp[wave] = logf(expf(-dp * 0.5f) + 1e-8f) + 1.0f;  // s_pos
    }
    __syncthreads();
    if (tid == 0)
        spos_part[blockIdx.x] = sp[0] + sp[1] + sp[2] + sp[3];
}

// ---------------------------------------------------------------------------
// Kernel 2: persistent fused fp8 Z·Z^T + exp-sum, upper block-triangle.
// 512 blocks (2/CU), ~4 tiles each. K=128-chunk double buffer: prefetch of
// chunk c+1 issued right after the barrier publishing chunk c -> its drain
// (at the next barrier) finds it already landed. One partial store per block.
// ---------------------------------------------------------------------------
__global__ __launch_bounds__(256, 2) void pair_kernel(
    const unsigned char* __restrict__ z1n8, const float* __restrict__ hl,
    float* __restrict__ negp_part) {

    __shared__ unsigned char SA[2][128 * 128];   // 32 KB
    __shared__ unsigned char SB[2][128 * 128];   // 32 KB
    __shared__ float red[4];

    const int tid = threadIdx.x, wave = tid >> 6, lane = tid & 63;
    const int bid = blockIdx.x;
    const int wr = wave >> 1, wc = wave & 1;
    const int quad = lane >> 4, colL = lane & 15;
    const int c7 = colL & 7;
    const int rl = lane >> 3, cl = lane & 7;

    // stage one K=128 chunk (A 16KB + B 16KB), 8 GLDS16 per wave.
    // per issue: 64 lanes x 16B = 8 rows x 128B; stored 16B-block cl gets
    // logical block cl ^ rl (row&7 == rl, row groups 8-aligned).
    auto stage = [&](int buf, int sbi, int sbj, int kc) {
        const unsigned char* gA = z1n8 + (size_t)sbi * (128 * DIM);
        const unsigned char* gB = z1n8 + (size_t)sbj * (128 * DIM);
        const size_t so = (size_t)(wave * 32 + rl) * DIM + kc * 128 + ((cl ^ rl) << 4);
        unsigned char* dA = &SA[buf][(wave * 32) * 128];
        unsigned char* dB = &SB[buf][(wave * 32) * 128];
        #pragma unroll
        for (int q = 0; q < 4; ++q) {
            GLDS16(gA + so + q * 8 * DIM, dA + q * 1024);
            GLDS16(gB + so + q * 8 * DIM, dB + q * 1024);
        }
    };

    // one K=128 chunk: 16 ds_read_b128 + 16 mfma_scale per wave
    auto compute = [&](int buf, f32x4 (&accf)[4][4]) {
        const unsigned char* A = SA[buf];
        const unsigned char* B = SB[buf];
        int8v af[4], bf[4];
        #pragma unroll
        for (int m = 0; m < 4; ++m) {
            int base = (wr * 64 + m * 16 + colL) * 128;
            union { int8v v; uint4 q[2]; } u8;
            u8.q[0] = *(const uint4*)&A[base + (((quad * 2    ) ^ c7) << 4)];
            u8.q[1] = *(const uint4*)&A[base + (((quad * 2 + 1) ^ c7) << 4)];
            af[m] = u8.v;
        }
        #pragma unroll
        for (int n = 0; n < 4; ++n) {
            int base = (wc * 64 + n * 16 + colL) * 128;
            union { int8v v; uint4 q[2]; } u8;
            u8.q[0] = *(const uint4*)&B[base + (((quad * 2    ) ^ c7) << 4)];
            u8.q[1] = *(const uint4*)&B[base + (((quad * 2 + 1) ^ c7) << 4)];
            bf[n] = u8.v;
        }
        #pragma unroll
        for (int m = 0; m < 4; ++m)
            #pragma unroll
            for (int n = 0; n < 4; ++n)
                accf[m][n] = __builtin_amdgcn_mfma_scale_f32_16x16x128_f8f6f4(
                    af[m], bf[n], accf[m][n],
                    0 /*fmtA=fp8*/, 0 /*fmtB=fp8*/,
                    0, 0x7F7F7F7F,   // scale A = 1.0 (E8M0 127)
                    0, 0x7F7F7F7F);  // scale B = 1.0
    };

    const int ntiles = (NBLK - 1 - bid) / GRID + 1;      // 4 or 5
    const int nch = ntiles * 2;                          // chunks: (tile, kc)

    float total = 0.0f;
    int bi, bj, nbi, nbj;
    tri_decode(bid, bi, bj);
    nbi = bi; nbj = bj;

    f32x4 accf[4][4];
    float hjn[4], hiv[4][4];

    stage(0, bi, bj, 0);                                 // prologue: chunk 0

    for (int ci = 0; ci < nch; ++ci) {
        const int cur = ci & 1;                          // buffer == kc
        const int kc  = ci & 1;

        __syncthreads();          // publish buf[cur] (its DMA had a full
                                  // compute phase to land)

        if (ci + 1 < nch) {                              // prefetch chunk ci+1
            if (kc == 0) {
                stage(1, bi, bj, 1);                     // same tile, chunk 1
            } else {
                tri_decode(bid + ((ci + 1) >> 1) * GRID, nbi, nbj);
                stage(0, nbi, nbj, 0);                   // next tile, chunk 0
            }
        }

        if (kc == 0) {
            #pragma unroll
            for (int m = 0; m < 4; ++m)
                #pragma unroll
                for (int n = 0; n < 4; ++n)
                    accf[m][n] = f32x4{0.f, 0.f, 0.f, 0.f};
            // preload hl for this tile (hidden under MFMA)
            #pragma unroll
            for (int n = 0; n < 4; ++n)
                hjn[n] = hl[bj * 128 + wc * 64 + n * 16 + colL];
            #pragma unroll
            for (int m = 0; m < 4; ++m)
                #pragma unroll
                for (int r = 0; r < 4; ++r)
                    hiv[m][r] = hl[bi * 128 + wr * 64 + m * 16 + quad * 4 + r];
        }

        compute(cur, accf);

        if (kc == 1) {
            // epilogue: term = exp2(min(dot*log2e - h_i - h_j, 0)), skip i==j
            float local = 0.0f;
            if (bi != bj) {
                #pragma unroll
                for (int m = 0; m < 4; ++m)
                    #pragma unroll
                    for (int reg = 0; reg < 4; ++reg)
                        #pragma unroll
                        for (int n = 0; n < 4; ++n) {
                            float arg = fminf(accf[m][n][reg] * LOG2E - hiv[m][reg] - hjn[n], 0.0f);
                            local += __builtin_amdgcn_exp2f(arg);
                        }
                local *= 2.0f;                           // mirrored block
            } else {
                #pragma unroll
                for (int m = 0; m < 4; ++m)
                    #pragma unroll
                    for (int reg = 0; reg < 4; ++reg) {
                        int i = wr * 64 + m * 16 + quad * 4 + reg;
                        #pragma unroll
                        for (int n = 0; n < 4; ++n) {
                            int j = wc * 64 + n * 16 + colL;
                            float arg = fminf(accf[m][n][reg] * LOG2E - hiv[m][reg] - hjn[n], 0.0f);
                            float e = __builtin_amdgcn_exp2f(arg);
                            local += (i == j) ? 0.0f : e;
                        }
                    }
            }
            total += local;
            bi = nbi; bj = nbj;
        }
    }

    // block-level reduction, once per kernel
    #pragma unroll
    for (int off = 32; off; off >>= 1) total += __shfl_down(total, off);
    if (lane == 0) red[wave] = total;
    __syncthreads();
    if (tid == 0)
        negp_part[bid] = red[0] + red[1] + red[2] + red[3];
}

// ---------------------------------------------------------------------------
// Kernel 3: finalize — reduce partials in double, emit scalar.
// ---------------------------------------------------------------------------
__global__ __launch_bounds__(256) void finalize_kernel(
    const float* __restrict__ spos_part, const float* __restrict__ negp_part,
    float* __restrict__ out) {

    int tid = threadIdx.x;
    double s = 0.0, ng = 0.0;
    for (int i = tid; i < 2048; i += 256) s  += (double)spos_part[i];
    for (int i = tid; i < GRID; i += 256) ng += (double)negp_part[i];

    #pragma unroll
    for (int off = 32; off; off >>= 1) {
        s  += __shfl_xor(s,  off);
        ng += __shfl_xor(ng, off);
    }
    __shared__ double sd[4], nd[4];
    int wave = tid >> 6, lane = tid & 63;
    if (lane == 0) { sd[wave] = s; nd[wave] = ng; }
    __syncthreads();
    if (tid == 0) {
        double st = sd[0] + sd[1] + sd[2] + sd[3];
        double nt = nd[0] + nd[1] + nd[2] + nd[3];
        double mean_star = nt / (8192.0 * 8191.0) + 1e-8;
        out[0] = (float)(-st / 8192.0 + 1.5 * mean_star);
    }
}

extern "C" void kernel_launch(void* const* d_in, const int* in_sizes, int n_in,
                              void* d_out, int out_size, void* d_ws, size_t ws_size,
                              hipStream_t stream) {
    const float* z1 = (const float*)d_in[0];
    const float* z2 = (const float*)d_in[1];
    float* out = (float*)d_out;

    char* ws = (char*)d_ws;
    float* hl            = (float*)ws;                                 // 32 KB
    unsigned char* z1n8  = (unsigned char*)(ws + N_ROWS * 4);          // 2 MB fp8
    float* spos_part     = (float*)(ws + N_ROWS * 4 + N_ROWS * DIM);   // 8 KB
    float* negp_part     = spos_part + 2048;                           // 2 KB

    norm_kernel<<<N_ROWS / 4, 256, 0, stream>>>(z1, z2, z1n8, hl, spos_part);
    pair_kernel<<<GRID, 256, 0, stream>>>(z1n8, hl, negp_part);
    finalize_kernel<<<1, 256, 0, stream>>>(spos_part, negp_part, out);
}